// Round 2
// baseline (294.872 us; speedup 1.0000x reference)
//
#include <hip/hip_runtime.h>

#define BINS 10

// Rewrite of GHM-C as a single streaming pass.
// Key algebra: loss = (1/n_nonempty) * sum_b ( bce_sum[b] / count[b] )  (tot cancels).
// With t in {0,1}: q = (1-2t)*p gives g = sigmoid(q), bce = softplus(q).
// Bin(g) at edges k/10  <=>  compare q against logit(k/10) (monotone) -> no sigmoid/div.
// Accumulate cumulative-GE sums/counts; difference them in finalize.
// Counts go through ballot+popcount (scalar pipe), sums through cndmask (1 VALU).
//
// ws layout: float part[20][grid]  (rows 0..9 = S_ge[k] partials, 10..19 = C_ge[k])
// Plain stores -> no zero-init kernel needed. 2 dispatches total.

__global__ __launch_bounds__(256) void ghmc_main(
    const float* __restrict__ pred, const float* __restrict__ targ,
    const float* __restrict__ lw, float* __restrict__ part, int n, int grid) {

    // logit(k/10), k=1..9
    const float T0 = -2.19722458f, T1 = -1.38629436f, T2 = -0.84729786f,
                T3 = -0.40546511f, T4 = 0.0f,         T5 =  0.40546511f,
                T6 =  0.84729786f, T7 =  1.38629436f, T8 =  2.19722458f;
    const float T[9] = {T0,T1,T2,T3,T4,T5,T6,T7,T8};

    float S[10];   // S[0] = total valid bce; S[k] = bce sum where g >= k/10
    int   C[10];   // wave-uniform cumulative counts (via ballot/popcount)
#pragma unroll
    for (int k = 0; k < 10; ++k) { S[k] = 0.0f; C[k] = 0; }

    const int tid    = blockIdx.x * blockDim.x + threadIdx.x;
    const int stride = grid * blockDim.x;
    const int nvec   = n >> 2;

    const float4* p4 = (const float4*)pred;
    const float4* t4 = (const float4*)targ;
    const float4* w4 = (const float4*)lw;

    for (int i = tid; i < nvec; i += stride) {
        float4 p = p4[i], t = t4[i], w = w4[i];
        const float* pp = (const float*)&p;
        const float* tt = (const float*)&t;
        const float* ww = (const float*)&w;
#pragma unroll
        for (int e = 0; e < 4; ++e) {
            float pk = pp[e], tk = tt[e], wk = ww[e];
            float m  = fmaf(-2.0f, tk, 1.0f);   // +1 or -1 (t in {0,1})
            float q  = m * pk;                  // g = sigmoid(q), bce = softplus(q)
            bool  valid = wk > 0.0f;
            float qm = valid ? q : -1.0e30f;    // invalid fails every threshold
            float u  = __expf(-fabsf(q));       // v_exp_f32 path
            float bce = fmaxf(q, 0.0f) + __logf(1.0f + u);
            float bw  = bce * wk;               // masked bce (w in {0,1})
            S[0] += bw;
            C[0] += (int)__popcll(__ballot(valid));
#pragma unroll
            for (int j = 0; j < 9; ++j) {
                bool pr = qm >= T[j];
                C[j + 1] += (int)__popcll(__ballot(pr));   // SALU popcount
                S[j + 1] += pr ? bw : 0.0f;                // cndmask + add
            }
        }
    }
    // scalar tail (n % 4): same ballot scheme; only low lanes of wave 0/block 0 active,
    // lane 0 is among them, so lane-0 readout below stays correct.
    {
        int rem = n & 3;
        if (tid < rem) {
            int idx = (nvec << 2) + tid;
            float pk = pred[idx], tk = targ[idx], wk = lw[idx];
            float m  = fmaf(-2.0f, tk, 1.0f);
            float q  = m * pk;
            bool  valid = wk > 0.0f;
            float qm = valid ? q : -1.0e30f;
            float u  = __expf(-fabsf(q));
            float bce = fmaxf(q, 0.0f) + __logf(1.0f + u);
            float bw  = bce * wk;
            S[0] += bw;
            C[0] += (int)__popcll(__ballot(valid));
#pragma unroll
            for (int j = 0; j < 9; ++j) {
                bool pr = qm >= T[j];
                C[j + 1] += (int)__popcll(__ballot(pr));
                S[j + 1] += pr ? bw : 0.0f;
            }
        }
    }

    // ---- reduce within block ----
    __shared__ float sS[BINS];
    __shared__ float sC[BINS];
    if (threadIdx.x < BINS) { sS[threadIdx.x] = 0.0f; sC[threadIdx.x] = 0.0f; }
    __syncthreads();

    const int lane = threadIdx.x & 63;
#pragma unroll
    for (int k = 0; k < BINS; ++k) {
        float s = S[k];
#pragma unroll
        for (int off = 32; off > 0; off >>= 1) s += __shfl_xor(s, off, 64);
        if (lane == 0) {
            atomicAdd(&sS[k], s);
            atomicAdd(&sC[k], (float)C[k]);   // C[k] wave-uniform; <=2560/wave, exact in f32
        }
    }
    __syncthreads();

    if (threadIdx.x < BINS) {
        part[threadIdx.x * grid + blockIdx.x]          = sS[threadIdx.x];
        part[(BINS + threadIdx.x) * grid + blockIdx.x] = sC[threadIdx.x];
    }
}

__global__ __launch_bounds__(256) void ghmc_fin(
    const float* __restrict__ part, float* __restrict__ out, int grid) {
    __shared__ float rows[2 * BINS];
    __shared__ float wsum[4];
    for (int k = 0; k < 2 * BINS; ++k) {
        float v = 0.0f;
        for (int i = threadIdx.x; i < grid; i += 256) v += part[k * grid + i];
#pragma unroll
        for (int off = 32; off > 0; off >>= 1) v += __shfl_xor(v, off, 64);
        if ((threadIdx.x & 63) == 0) wsum[threadIdx.x >> 6] = v;
        __syncthreads();
        if (threadIdx.x == 0) rows[k] = wsum[0] + wsum[1] + wsum[2] + wsum[3];
        __syncthreads();
    }
    if (threadIdx.x == 0) {
        float acc = 0.0f;
        int   nb  = 0;
#pragma unroll
        for (int b = 0; b < BINS; ++b) {
            float sN = (b < BINS - 1) ? rows[b + 1]        : 0.0f;
            float cN = (b < BINS - 1) ? rows[BINS + b + 1] : 0.0f;
            float s  = rows[b] - sN;          // per-bin bce sum
            float c  = rows[BINS + b] - cN;   // per-bin valid count
            if (c > 0.5f) { nb += 1; acc += s / c; }
        }
        out[0] = (nb > 0) ? (acc / (float)nb) : 0.0f;  // LOSS_WEIGHT = 1
    }
}

extern "C" void kernel_launch(void* const* d_in, const int* in_sizes, int n_in,
                              void* d_out, int out_size, void* d_ws, size_t ws_size,
                              hipStream_t stream) {
    const float* pred = (const float*)d_in[0];
    const float* targ = (const float*)d_in[1];
    const float* lw   = (const float*)d_in[2];
    float* out  = (float*)d_out;
    float* part = (float*)d_ws;
    const int n = in_sizes[0];   // 20,971,520

    int grid = 2048;             // 8 blocks/CU, grid-stride
    size_t need = (size_t)grid * 2 * BINS * sizeof(float);
    if (ws_size < need) {        // safeguard: shrink grid to fit workspace
        grid = (int)(ws_size / (2 * BINS * sizeof(float)));
        if (grid < 1) grid = 1;
    }

    ghmc_main<<<grid, 256, 0, stream>>>(pred, targ, lw, part, n, grid);
    ghmc_fin<<<1, 256, 0, stream>>>(part, out, grid);
}

// Round 3
// 291.123 us; speedup vs baseline: 1.0129x; 1.0129x over previous
//
#include <hip/hip_runtime.h>

#define BINS 10

// GHM-C, momentum=0, single streaming pass.
// loss = (1/n_nonempty) * sum_b ( bce_sum[b] / count[b] )    (tot cancels)
// t in {0,1}: q = (1-2t)*p  =>  g = sigmoid(q), bce = softplus(q).
// bin(g) at edges k/10  <=>  q >= logit(k/10)  (monotone, no sigmoid/div).
// Accumulate cumulative-GE sums/counts per lane (pure VALU, no ballot/SALU),
// difference cumulative rows in the finalize kernel.
// ws: float part[20][grid]  rows 0..9 = S_ge[k], rows 10..19 = C_ge[k].

__device__ __forceinline__ void ghmc_elem(float pk, float tk, float wk,
                                          float* __restrict__ S,
                                          float* __restrict__ C,
                                          const float* __restrict__ T) {
    float m  = fmaf(-2.0f, tk, 1.0f);     // +1 / -1
    float q  = m * pk;
    bool  valid = wk > 0.0f;
    float qm = valid ? q : -1.0e30f;      // invalid fails every threshold
    float u  = __expf(-fabsf(q));         // v_exp_f32
    float bce = fmaxf(q, 0.0f) + __logf(1.0f + u);
    float bw  = bce * wk;                 // w in {0,1} masks invalid
    S[0] += bw;
    C[0] += valid ? 1.0f : 0.0f;
#pragma unroll
    for (int j = 0; j < 9; ++j) {
        bool pr = qm >= T[j];             // one v_cmp shared by both updates
        S[j + 1] += pr ? bw : 0.0f;       // cndmask + add
        C[j + 1] += pr ? 1.0f : 0.0f;     // cndmask + add (per-lane, no SALU)
    }
}

__device__ __forceinline__ void ghmc_vec4(float4 p, float4 t, float4 w,
                                          float* S, float* C, const float* T) {
    const float* pp = (const float*)&p;
    const float* tt = (const float*)&t;
    const float* ww = (const float*)&w;
#pragma unroll
    for (int e = 0; e < 4; ++e) ghmc_elem(pp[e], tt[e], ww[e], S, C, T);
}

__global__ __launch_bounds__(256) void ghmc_main(
    const float* __restrict__ pred, const float* __restrict__ targ,
    const float* __restrict__ lw, float* __restrict__ part, int n, int grid) {

    const float T[9] = {-2.19722458f, -1.38629436f, -0.84729786f, -0.40546511f,
                        0.0f, 0.40546511f, 0.84729786f, 1.38629436f, 2.19722458f};

    float S[BINS], C[BINS];
#pragma unroll
    for (int k = 0; k < BINS; ++k) { S[k] = 0.0f; C[k] = 0.0f; }

    const int tid    = blockIdx.x * blockDim.x + threadIdx.x;
    const int stride = grid * blockDim.x;
    const int nvec   = n >> 2;

    const float4* p4 = (const float4*)pred;
    const float4* t4 = (const float4*)targ;
    const float4* w4 = (const float4*)lw;

    int i = tid;
    // unroll-2: 6 float4 loads in flight before any compute
    for (; i + stride < nvec; i += 2 * stride) {
        const int i2 = i + stride;
        float4 pA = p4[i],  tA = t4[i],  wA = w4[i];
        float4 pB = p4[i2], tB = t4[i2], wB = w4[i2];
        ghmc_vec4(pA, tA, wA, S, C, T);
        ghmc_vec4(pB, tB, wB, S, C, T);
    }
    for (; i < nvec; i += stride) ghmc_vec4(p4[i], t4[i], w4[i], S, C, T);
    {   // scalar tail (n % 4) — per-lane accumulators, no wave assumptions
        int rem = n & 3;
        if (tid < rem) {
            int idx = (nvec << 2) + tid;
            ghmc_elem(pred[idx], targ[idx], lw[idx], S, C, T);
        }
    }

    // ---- block reduction: wave butterfly -> LDS atomics -> per-block store ----
    __shared__ float sS[BINS];
    __shared__ float sC[BINS];
    if (threadIdx.x < BINS) { sS[threadIdx.x] = 0.0f; sC[threadIdx.x] = 0.0f; }
    __syncthreads();

    const int lane = threadIdx.x & 63;
#pragma unroll
    for (int k = 0; k < BINS; ++k) {
        float s = S[k], c = C[k];
#pragma unroll
        for (int off = 32; off > 0; off >>= 1) {
            s += __shfl_xor(s, off, 64);
            c += __shfl_xor(c, off, 64);
        }
        if (lane == 0) { atomicAdd(&sS[k], s); atomicAdd(&sC[k], c); }
    }
    __syncthreads();

    if (threadIdx.x < BINS) {
        part[threadIdx.x * grid + blockIdx.x]          = sS[threadIdx.x];
        part[(BINS + threadIdx.x) * grid + blockIdx.x] = sC[threadIdx.x];
    }
}

__global__ __launch_bounds__(256) void ghmc_fin(
    const float* __restrict__ part, float* __restrict__ out, int grid) {
    __shared__ float rows[2 * BINS];
    __shared__ float wsum[4];
    for (int k = 0; k < 2 * BINS; ++k) {
        float v = 0.0f;
        for (int i = threadIdx.x; i < grid; i += 256) v += part[k * grid + i];
#pragma unroll
        for (int off = 32; off > 0; off >>= 1) v += __shfl_xor(v, off, 64);
        if ((threadIdx.x & 63) == 0) wsum[threadIdx.x >> 6] = v;
        __syncthreads();
        if (threadIdx.x == 0) rows[k] = wsum[0] + wsum[1] + wsum[2] + wsum[3];
        __syncthreads();
    }
    if (threadIdx.x == 0) {
        float acc = 0.0f;
        int   nb  = 0;
#pragma unroll
        for (int b = 0; b < BINS; ++b) {
            float sN = (b < BINS - 1) ? rows[b + 1]        : 0.0f;
            float cN = (b < BINS - 1) ? rows[BINS + b + 1] : 0.0f;
            float s  = rows[b] - sN;          // per-bin bce sum
            float c  = rows[BINS + b] - cN;   // per-bin valid count
            if (c > 0.5f) { nb += 1; acc += s / c; }
        }
        out[0] = (nb > 0) ? (acc / (float)nb) : 0.0f;  // LOSS_WEIGHT = 1
    }
}

extern "C" void kernel_launch(void* const* d_in, const int* in_sizes, int n_in,
                              void* d_out, int out_size, void* d_ws, size_t ws_size,
                              hipStream_t stream) {
    const float* pred = (const float*)d_in[0];
    const float* targ = (const float*)d_in[1];
    const float* lw   = (const float*)d_in[2];
    float* out  = (float*)d_out;
    float* part = (float*)d_ws;
    const int n = in_sizes[0];   // 20,971,520

    int grid = 2048;             // 8 blocks/CU; nvec/threads = exactly 10 iters
    size_t need = (size_t)grid * 2 * BINS * sizeof(float);
    if (ws_size < need) {
        grid = (int)(ws_size / (2 * BINS * sizeof(float)));
        if (grid < 1) grid = 1;
    }

    ghmc_main<<<grid, 256, 0, stream>>>(pred, targ, lw, part, n, grid);
    ghmc_fin<<<1, 256, 0, stream>>>(part, out, grid);
}

// Round 4
// 290.654 us; speedup vs baseline: 1.0145x; 1.0016x over previous
//
#include <hip/hip_runtime.h>

#define BINS 10

// GHM-C, momentum=0, single streaming pass.
// loss = (1/n_nonempty) * sum_b ( bce_sum[b] / count[b] )    (tot cancels)
// t in {0,1}: q = (1-2t)*p  =>  g = sigmoid(q), bce = softplus(q).
// bin(g) at edges k/10  <=>  q >= logit(k/10)  (monotone; no sigmoid/div).
// Cumulative-GE sums/counts; difference rows in finalize.
//
// R3 fix: accumulators are 20 NAMED SCALARS, element math is a macro.
// R0-R2 used local arrays passed by pointer into a helper -> compiler spilled
// them to scratch (VGPR_Count=28 all rounds; dur pinned at ~104us even when
// inputs were fully L3-resident). No arrays, no pointers, no spill.
//
// ws: float part[20][grid]  rows 0..9 = S_ge[k], rows 10..19 = C_ge[k].

#define GHMC_THRESH(Tj, Sj, Cj)                                        \
    { bool pr = qm >= (Tj);                                            \
      Sj += pr ? bw : 0.0f;                                            \
      Cj += pr ? 1.0f : 0.0f; }

#define GHMC_ELEM(pk, tk, wk)                                          \
    do {                                                               \
        float m_  = fmaf(-2.0f, (tk), 1.0f);   /* +1 / -1 */           \
        float q   = m_ * (pk);                                         \
        bool  valid = (wk) > 0.0f;                                     \
        float qm  = valid ? q : -1.0e30f;                              \
        float u_  = __expf(-fabsf(q));                                 \
        float bce = fmaxf(q, 0.0f) + __logf(1.0f + u_);                \
        float bw  = bce * (wk);                                        \
        S0 += bw;                                                      \
        C0 += valid ? 1.0f : 0.0f;                                     \
        GHMC_THRESH(-2.19722458f, S1, C1)                              \
        GHMC_THRESH(-1.38629436f, S2, C2)                              \
        GHMC_THRESH(-0.84729786f, S3, C3)                              \
        GHMC_THRESH(-0.40546511f, S4, C4)                              \
        GHMC_THRESH( 0.0f,        S5, C5)                              \
        GHMC_THRESH( 0.40546511f, S6, C6)                              \
        GHMC_THRESH( 0.84729786f, S7, C7)                              \
        GHMC_THRESH( 1.38629436f, S8, C8)                              \
        GHMC_THRESH( 2.19722458f, S9, C9)                              \
    } while (0)

#define GHMC_REDUCE(k, Sk, Ck)                                         \
    {                                                                  \
        float s = Sk, c = Ck;                                          \
        _Pragma("unroll")                                              \
        for (int off = 32; off > 0; off >>= 1) {                       \
            s += __shfl_xor(s, off, 64);                               \
            c += __shfl_xor(c, off, 64);                               \
        }                                                              \
        if (lane == 0) { atomicAdd(&sS[k], s); atomicAdd(&sC[k], c); } \
    }

__global__ __launch_bounds__(256) void ghmc_main(
    const float* __restrict__ pred, const float* __restrict__ targ,
    const float* __restrict__ lw, float* __restrict__ part, int n, int grid) {

    float S0 = 0.f, S1 = 0.f, S2 = 0.f, S3 = 0.f, S4 = 0.f,
          S5 = 0.f, S6 = 0.f, S7 = 0.f, S8 = 0.f, S9 = 0.f;
    float C0 = 0.f, C1 = 0.f, C2 = 0.f, C3 = 0.f, C4 = 0.f,
          C5 = 0.f, C6 = 0.f, C7 = 0.f, C8 = 0.f, C9 = 0.f;

    const int tid    = blockIdx.x * blockDim.x + threadIdx.x;
    const int stride = grid * blockDim.x;
    const int nvec   = n >> 2;

    const float4* p4 = (const float4*)pred;
    const float4* t4 = (const float4*)targ;
    const float4* w4 = (const float4*)lw;

    for (int i = tid; i < nvec; i += stride) {
        float4 p = p4[i], t = t4[i], w = w4[i];
        GHMC_ELEM(p.x, t.x, w.x);
        GHMC_ELEM(p.y, t.y, w.y);
        GHMC_ELEM(p.z, t.z, w.z);
        GHMC_ELEM(p.w, t.w, w.w);
    }
    {   // scalar tail (n % 4)
        int rem = n & 3;
        if (tid < rem) {
            int idx = (nvec << 2) + tid;
            float pk = pred[idx], tk = targ[idx], wk = lw[idx];
            GHMC_ELEM(pk, tk, wk);
        }
    }

    // ---- block reduction: wave butterfly -> LDS atomics -> per-block store ----
    __shared__ float sS[BINS];
    __shared__ float sC[BINS];
    if (threadIdx.x < BINS) { sS[threadIdx.x] = 0.0f; sC[threadIdx.x] = 0.0f; }
    __syncthreads();

    const int lane = threadIdx.x & 63;
    GHMC_REDUCE(0, S0, C0)
    GHMC_REDUCE(1, S1, C1)
    GHMC_REDUCE(2, S2, C2)
    GHMC_REDUCE(3, S3, C3)
    GHMC_REDUCE(4, S4, C4)
    GHMC_REDUCE(5, S5, C5)
    GHMC_REDUCE(6, S6, C6)
    GHMC_REDUCE(7, S7, C7)
    GHMC_REDUCE(8, S8, C8)
    GHMC_REDUCE(9, S9, C9)
    __syncthreads();

    if (threadIdx.x < BINS) {
        part[threadIdx.x * grid + blockIdx.x]          = sS[threadIdx.x];
        part[(BINS + threadIdx.x) * grid + blockIdx.x] = sC[threadIdx.x];
    }
}

__global__ __launch_bounds__(256) void ghmc_fin(
    const float* __restrict__ part, float* __restrict__ out, int grid) {
    __shared__ float rows[2 * BINS];
    __shared__ float wsum[4];
    for (int k = 0; k < 2 * BINS; ++k) {
        float v = 0.0f;
        for (int i = threadIdx.x; i < grid; i += 256) v += part[k * grid + i];
#pragma unroll
        for (int off = 32; off > 0; off >>= 1) v += __shfl_xor(v, off, 64);
        if ((threadIdx.x & 63) == 0) wsum[threadIdx.x >> 6] = v;
        __syncthreads();
        if (threadIdx.x == 0) rows[k] = wsum[0] + wsum[1] + wsum[2] + wsum[3];
        __syncthreads();
    }
    if (threadIdx.x == 0) {
        float acc = 0.0f;
        int   nb  = 0;
#pragma unroll
        for (int b = 0; b < BINS; ++b) {
            float sN = (b < BINS - 1) ? rows[b + 1]        : 0.0f;
            float cN = (b < BINS - 1) ? rows[BINS + b + 1] : 0.0f;
            float s  = rows[b] - sN;          // per-bin bce sum
            float c  = rows[BINS + b] - cN;   // per-bin valid count
            if (c > 0.5f) { nb += 1; acc += s / c; }
        }
        out[0] = (nb > 0) ? (acc / (float)nb) : 0.0f;  // LOSS_WEIGHT = 1
    }
}

extern "C" void kernel_launch(void* const* d_in, const int* in_sizes, int n_in,
                              void* d_out, int out_size, void* d_ws, size_t ws_size,
                              hipStream_t stream) {
    const float* pred = (const float*)d_in[0];
    const float* targ = (const float*)d_in[1];
    const float* lw   = (const float*)d_in[2];
    float* out  = (float*)d_out;
    float* part = (float*)d_ws;
    const int n = in_sizes[0];   // 20,971,520

    int grid = 2048;             // 8 blocks/CU; nvec/threads = exactly 10 iters
    size_t need = (size_t)grid * 2 * BINS * sizeof(float);
    if (ws_size < need) {
        grid = (int)(ws_size / (2 * BINS * sizeof(float)));
        if (grid < 1) grid = 1;
    }

    ghmc_main<<<grid, 256, 0, stream>>>(pred, targ, lw, part, n, grid);
    ghmc_fin<<<1, 256, 0, stream>>>(part, out, grid);
}

// Round 5
// 289.543 us; speedup vs baseline: 1.0184x; 1.0038x over previous
//
#include <hip/hip_runtime.h>

#define BINS 10

// GHM-C, momentum=0, single streaming pass.
// loss = (1/n_nonempty) * sum_b ( bce_sum[b] / count[b] )    (tot cancels)
// t in {0,1}: q = (1-2t)*p  =>  g = sigmoid(q), bce = softplus(q).
// bin(g) at edges k/10  <=>  q >= logit(k/10)  (monotone; no sigmoid/div).
// Cumulative-GE sums/counts; difference rows in finalize.
//
// R4 fix: __launch_bounds__(256, 4). R0-R3 all compiled to 28-32 VGPRs --
// the backend's max-occupancy heuristic (8 waves/EU => <=64 VGPR) was
// register-starving the kernel and re-serializing it (dur ~105us regardless
// of VALU count or memory residency). (256,4) raises the cap to ~128 VGPR:
// room for 20 live accumulators + a 2-deep hoisted load pipeline.
//
// ws: float part[20][grid]  rows 0..9 = S_ge[k], rows 10..19 = C_ge[k].

#define GHMC_THRESH(Tj, Sj, Cj)                                        \
    { bool pr = qm >= (Tj);                                            \
      Sj += pr ? bw : 0.0f;                                            \
      Cj += pr ? 1.0f : 0.0f; }

#define GHMC_ELEM(pk, tk, wk)                                          \
    do {                                                               \
        float m_  = fmaf(-2.0f, (tk), 1.0f);   /* +1 / -1 */           \
        float q   = m_ * (pk);                                         \
        bool  valid = (wk) > 0.0f;                                     \
        float qm  = valid ? q : -1.0e30f;                              \
        float u_  = __expf(-fabsf(q));                                 \
        float bce = fmaxf(q, 0.0f) + __logf(1.0f + u_);                \
        float bw  = bce * (wk);                                        \
        S0 += bw;                                                      \
        C0 += valid ? 1.0f : 0.0f;                                     \
        GHMC_THRESH(-2.19722458f, S1, C1)                              \
        GHMC_THRESH(-1.38629436f, S2, C2)                              \
        GHMC_THRESH(-0.84729786f, S3, C3)                              \
        GHMC_THRESH(-0.40546511f, S4, C4)                              \
        GHMC_THRESH( 0.0f,        S5, C5)                              \
        GHMC_THRESH( 0.40546511f, S6, C6)                              \
        GHMC_THRESH( 0.84729786f, S7, C7)                              \
        GHMC_THRESH( 1.38629436f, S8, C8)                              \
        GHMC_THRESH( 2.19722458f, S9, C9)                              \
    } while (0)

#define GHMC_REDUCE(k, Sk, Ck)                                         \
    {                                                                  \
        float s = Sk, c = Ck;                                          \
        _Pragma("unroll")                                              \
        for (int off = 32; off > 0; off >>= 1) {                       \
            s += __shfl_xor(s, off, 64);                               \
            c += __shfl_xor(c, off, 64);                               \
        }                                                              \
        if (lane == 0) { atomicAdd(&sS[k], s); atomicAdd(&sC[k], c); } \
    }

__global__ __launch_bounds__(256, 4) void ghmc_main(
    const float* __restrict__ pred, const float* __restrict__ targ,
    const float* __restrict__ lw, float* __restrict__ part, int n, int grid) {

    float S0 = 0.f, S1 = 0.f, S2 = 0.f, S3 = 0.f, S4 = 0.f,
          S5 = 0.f, S6 = 0.f, S7 = 0.f, S8 = 0.f, S9 = 0.f;
    float C0 = 0.f, C1 = 0.f, C2 = 0.f, C3 = 0.f, C4 = 0.f,
          C5 = 0.f, C6 = 0.f, C7 = 0.f, C8 = 0.f, C9 = 0.f;

    const int tid    = blockIdx.x * blockDim.x + threadIdx.x;
    const int stride = grid * blockDim.x;
    const int nvec   = n >> 2;

    const float4* p4 = (const float4*)pred;
    const float4* t4 = (const float4*)targ;
    const float4* w4 = (const float4*)lw;

    int i = tid;
    // unroll-2 with all 6 float4 loads hoisted: now that the register budget
    // allows it, both bundles stay live -> 6 outstanding loads, real ILP.
    for (; i + stride < nvec; i += 2 * stride) {
        const int i2 = i + stride;
        float4 pA = p4[i],  tA = t4[i],  wA = w4[i];
        float4 pB = p4[i2], tB = t4[i2], wB = w4[i2];
        GHMC_ELEM(pA.x, tA.x, wA.x);
        GHMC_ELEM(pA.y, tA.y, wA.y);
        GHMC_ELEM(pA.z, tA.z, wA.z);
        GHMC_ELEM(pA.w, tA.w, wA.w);
        GHMC_ELEM(pB.x, tB.x, wB.x);
        GHMC_ELEM(pB.y, tB.y, wB.y);
        GHMC_ELEM(pB.z, tB.z, wB.z);
        GHMC_ELEM(pB.w, tB.w, wB.w);
    }
    for (; i < nvec; i += stride) {
        float4 p = p4[i], t = t4[i], w = w4[i];
        GHMC_ELEM(p.x, t.x, w.x);
        GHMC_ELEM(p.y, t.y, w.y);
        GHMC_ELEM(p.z, t.z, w.z);
        GHMC_ELEM(p.w, t.w, w.w);
    }
    {   // scalar tail (n % 4)
        int rem = n & 3;
        if (tid < rem) {
            int idx = (nvec << 2) + tid;
            float pk = pred[idx], tk = targ[idx], wk = lw[idx];
            GHMC_ELEM(pk, tk, wk);
        }
    }

    // ---- block reduction: wave butterfly -> LDS atomics -> per-block store ----
    __shared__ float sS[BINS];
    __shared__ float sC[BINS];
    if (threadIdx.x < BINS) { sS[threadIdx.x] = 0.0f; sC[threadIdx.x] = 0.0f; }
    __syncthreads();

    const int lane = threadIdx.x & 63;
    GHMC_REDUCE(0, S0, C0)
    GHMC_REDUCE(1, S1, C1)
    GHMC_REDUCE(2, S2, C2)
    GHMC_REDUCE(3, S3, C3)
    GHMC_REDUCE(4, S4, C4)
    GHMC_REDUCE(5, S5, C5)
    GHMC_REDUCE(6, S6, C6)
    GHMC_REDUCE(7, S7, C7)
    GHMC_REDUCE(8, S8, C8)
    GHMC_REDUCE(9, S9, C9)
    __syncthreads();

    if (threadIdx.x < BINS) {
        part[threadIdx.x * grid + blockIdx.x]          = sS[threadIdx.x];
        part[(BINS + threadIdx.x) * grid + blockIdx.x] = sC[threadIdx.x];
    }
}

__global__ __launch_bounds__(256) void ghmc_fin(
    const float* __restrict__ part, float* __restrict__ out, int grid) {
    __shared__ float rows[2 * BINS];
    __shared__ float wsum[4];
    for (int k = 0; k < 2 * BINS; ++k) {
        float v = 0.0f;
        for (int i = threadIdx.x; i < grid; i += 256) v += part[k * grid + i];
#pragma unroll
        for (int off = 32; off > 0; off >>= 1) v += __shfl_xor(v, off, 64);
        if ((threadIdx.x & 63) == 0) wsum[threadIdx.x >> 6] = v;
        __syncthreads();
        if (threadIdx.x == 0) rows[k] = wsum[0] + wsum[1] + wsum[2] + wsum[3];
        __syncthreads();
    }
    if (threadIdx.x == 0) {
        float acc = 0.0f;
        int   nb  = 0;
#pragma unroll
        for (int b = 0; b < BINS; ++b) {
            float sN = (b < BINS - 1) ? rows[b + 1]        : 0.0f;
            float cN = (b < BINS - 1) ? rows[BINS + b + 1] : 0.0f;
            float s  = rows[b] - sN;          // per-bin bce sum
            float c  = rows[BINS + b] - cN;   // per-bin valid count
            if (c > 0.5f) { nb += 1; acc += s / c; }
        }
        out[0] = (nb > 0) ? (acc / (float)nb) : 0.0f;  // LOSS_WEIGHT = 1
    }
}

extern "C" void kernel_launch(void* const* d_in, const int* in_sizes, int n_in,
                              void* d_out, int out_size, void* d_ws, size_t ws_size,
                              hipStream_t stream) {
    const float* pred = (const float*)d_in[0];
    const float* targ = (const float*)d_in[1];
    const float* lw   = (const float*)d_in[2];
    float* out  = (float*)d_out;
    float* part = (float*)d_ws;
    const int n = in_sizes[0];   // 20,971,520

    int grid = 2048;             // grid-stride; exactly 10 float4 iters/thread
    size_t need = (size_t)grid * 2 * BINS * sizeof(float);
    if (ws_size < need) {
        grid = (int)(ws_size / (2 * BINS * sizeof(float)));
        if (grid < 1) grid = 1;
    }

    ghmc_main<<<grid, 256, 0, stream>>>(pred, targ, lw, part, n, grid);
    ghmc_fin<<<1, 256, 0, stream>>>(part, out, grid);
}